// Round 1
// 1133.859 us; speedup vs baseline: 1.9340x; 1.9340x over previous
//
#include <hip/hip_runtime.h>
#include <stdint.h>

#define TSTEPS 1000
#define NB 256
#define NF 64
#define NH 256   // H1 == H2 == 256
#define CHUNK 8
#define NCH 125  // 125 * 8 == 1000, no tail

// Prep: transpose W2 (H2,H1) -> W2T[h1][h2] in d_ws for coalesced gathers,
// and zero the two global spike counters.
__global__ void snn_prep(const float* __restrict__ W2, float* __restrict__ W2T,
                         unsigned int* __restrict__ counts) {
    int idx = blockIdx.x * 256 + threadIdx.x;     // idx = h1*256 + h2
    W2T[idx] = W2[(idx & 255) * 256 + (idx >> 8)];
    if (idx < 2) counts[idx] = 0u;
}

// Main: one workgroup per batch, thread h = hidden unit (h1 for layer1 state,
// h2 for layer2 state). Time is processed in chunks of 8 steps: layer-1 for
// the whole chunk (no cross-wave deps, spk1 published to LDS), one barrier,
// then layer-2 for the whole chunk with pipelined independent L2 gathers.
// W1 lives in registers (64 VGPR/thread); dense masked accumulation replaces
// the serial sparse gather, preserving the exact fp32 summation order.
__launch_bounds__(256, 1)
__global__ void snn_main(const float* __restrict__ spikes,
                         const float* __restrict__ W1,
                         const float* __restrict__ b1,
                         const float* __restrict__ W2T,
                         const float* __restrict__ b2,
                         const float* __restrict__ Wr,
                         const float* __restrict__ br,
                         float* __restrict__ out,
                         unsigned int* __restrict__ counts) {
    const int b = blockIdx.x;
    const int h = threadIdx.x;
    const int lane = h & 63;
    const int wv = h >> 6;

    __shared__ unsigned char slist[CHUNK][256]; // per-step per-wave compacted spk1 lists
    __shared__ unsigned char scnt8[CHUNK * 4];  // per-step per-wave counts (bytes)
    __shared__ float rp0[4], rp1[4];
    __shared__ int rc1[4], rc2[4];

    // W1 row h -> registers: w1[f] = W1[h*64+f]. One-time 64 KB/block read,
    // W1 is L2/L3-resident after the first block touches it.
    float w1[64];
    {
        const float4* W1v = (const float4*)(W1 + h * NF);
        #pragma unroll
        for (int i = 0; i < 16; ++i) {
            float4 v = W1v[i];
            w1[4 * i + 0] = v.x; w1[4 * i + 1] = v.y;
            w1[4 * i + 2] = v.z; w1[4 * i + 3] = v.w;
        }
    }

    const float b1h = b1[h];
    const float b2h = b2[h];
    float mem1 = 0.f, mem2 = 0.f, mem2s = 0.f;
    int cnt1 = 0, cnt2 = 0;

    // Per-thread input prefetch: thread (any wave) needs x[t][b][lane] only.
    // Each wave's 64 lanes read 256 contiguous bytes -> coalesced; 4x wave
    // redundancy is served by L1. Prefetched one chunk ahead into registers.
    const size_t xstride = (size_t)NB * NF;
    const float* xbase = spikes + (size_t)b * NF + lane;
    float xq[CHUNK];
    #pragma unroll
    for (int tt = 0; tt < CHUNK; ++tt) {
        xq[tt] = xbase[(size_t)tt * xstride];
    }

    for (int c = 0; c < NCH; ++c) {
        __syncthreads();   // prev chunk's layer-2 slist reads complete; safe to overwrite

        // ---- layer 1: CHUNK steps, purely wave-local ----
        #pragma unroll
        for (int tt = 0; tt < CHUNK; ++tt) {
            unsigned long long xm = __ballot(xq[tt] > 0.f);
            // dense masked accumulation, 4 chains of 16 (ascending f within
            // each quarter) — bit-exact same order as the sparse ctz gather,
            // since adding +0.0f for inactive features is an exact identity.
            float a0 = 0.f, a1 = 0.f, a2 = 0.f, a3 = 0.f;
            #pragma unroll
            for (int f = 0; f < 16; ++f) {
                a0 += ((xm >> f) & 1ull) ? w1[f] : 0.f;
                a1 += ((xm >> (f + 16)) & 1ull) ? w1[f + 16] : 0.f;
                a2 += ((xm >> (f + 32)) & 1ull) ? w1[f + 32] : 0.f;
                a3 += ((xm >> (f + 48)) & 1ull) ? w1[f + 48] : 0.f;
            }
            float cur1 = b1h + ((a0 + a1) + (a2 + a3));
            float reset1 = (mem1 > 1.f) ? 1.f : 0.f;
            mem1 = 0.8187307530779818f * mem1 + cur1 - reset1;   // beta1 = exp(-1/5)
            bool s1 = (mem1 - 1.f) > 0.f;
            cnt1 += (int)s1;
            unsigned long long sm = __ballot(s1);
            if (lane == 0) scnt8[tt * 4 + wv] = (unsigned char)__popcll(sm);
            if (s1) {
                int rank = __popcll(sm & ((1ull << lane) - 1ull));
                slist[tt][(wv << 6) + rank] = (unsigned char)h;
            }
        }
        __syncthreads();   // slist/scnt published to all waves

        // prefetch next chunk's inputs; they land during the layer-2 phase
        {
            int cn = (c + 1 < NCH) ? c + 1 : 0;   // clamped dummy load on last chunk
            const float* xb = xbase + (size_t)cn * CHUNK * xstride;
            #pragma unroll
            for (int tt = 0; tt < CHUNK; ++tt) {
                xq[tt] = xb[(size_t)tt * xstride];
            }
        }

        // ---- layer 2: CHUNK steps, pipelined L2 gathers ----
        // Hoist all list metadata + first-4 indices into registers so the
        // unconditional gather loads for all 8 steps can be in flight at once.
        unsigned int cw[CHUNK], l0[CHUNK], l1[CHUNK], l2[CHUNK], l3[CHUNK];
        #pragma unroll
        for (int tt = 0; tt < CHUNK; ++tt) {
            cw[tt] = *(const unsigned int*)&scnt8[tt * 4];
            l0[tt] = *(const unsigned int*)&slist[tt][0];
            l1[tt] = *(const unsigned int*)&slist[tt][64];
            l2[tt] = *(const unsigned int*)&slist[tt][128];
            l3[tt] = *(const unsigned int*)&slist[tt][192];
        }
        const float* W2Th = W2T + h;
        #pragma unroll
        for (int tt = 0; tt < CHUNK; ++tt) {
            int c0 = cw[tt] & 255, c1 = (cw[tt] >> 8) & 255;
            int c2 = (cw[tt] >> 16) & 255, c3 = (cw[tt] >> 24) & 255;
            float q0 = 0.f, q1 = 0.f, q2 = 0.f, q3 = 0.f;
            unsigned int u0 = l0[tt], u1 = l1[tt], u2 = l2[tt], u3 = l3[tt];
            // first <=4 entries per wave-list, branch-free: stale bytes index
            // valid rows (0..255), their values are masked to 0 before the add,
            // so the summation order matches the guarded loop exactly.
            #pragma unroll
            for (int i = 0; i < 4; ++i) {
                float v0 = W2Th[(int)((u0 >> (8 * i)) & 255u) << 8];
                float v1 = W2Th[(int)((u1 >> (8 * i)) & 255u) << 8];
                float v2 = W2Th[(int)((u2 >> (8 * i)) & 255u) << 8];
                float v3 = W2Th[(int)((u3 >> (8 * i)) & 255u) << 8];
                q0 += (i < c0) ? v0 : 0.f;
                q1 += (i < c1) ? v1 : 0.f;
                q2 += (i < c2) ? v2 : 0.f;
                q3 += (i < c3) ? v3 : 0.f;
            }
            int nmax = max(max(c0, c1), max(c2, c3));
            if (nmax > 4) {   // rare overflow path (per-wave spike count > 4)
                const unsigned char* sl = slist[tt];
                for (int i = 4; i < nmax; ++i) {
                    if (i < c0) q0 += W2Th[(int)sl[i] << 8];
                    if (i < c1) q1 += W2Th[(int)sl[64 + i] << 8];
                    if (i < c2) q2 += W2Th[(int)sl[128 + i] << 8];
                    if (i < c3) q3 += W2Th[(int)sl[192 + i] << 8];
                }
            }
            float cur2 = b2h + ((q0 + q1) + (q2 + q3));
            float reset2 = (mem2 > 1.f) ? 1.f : 0.f;
            mem2 = 0.9048374180359595f * mem2 + cur2 - reset2;   // beta2 = exp(-1/10)
            bool s2 = (mem2 - 1.f) > 0.f;
            cnt2 += (int)s2;
            mem2s += mem2;
        }
    }

    // readout: out[b,:] = (mem2_sum/T) @ Wr.T + br ; block-level reduction
    float v = mem2s / 1000.0f;
    float p0 = v * Wr[h];
    float p1 = v * Wr[NH + h];
    int rcs1 = cnt1, rcs2 = cnt2;
    for (int off = 32; off > 0; off >>= 1) {
        p0 += __shfl_down(p0, off);
        p1 += __shfl_down(p1, off);
        rcs1 += __shfl_down(rcs1, off);
        rcs2 += __shfl_down(rcs2, off);
    }
    if (lane == 0) { rp0[wv] = p0; rp1[wv] = p1; rc1[wv] = rcs1; rc2[wv] = rcs2; }
    __syncthreads();
    if (h == 0) {
        out[2 * b]     = ((rp0[0] + rp0[1]) + (rp0[2] + rp0[3])) + br[0];
        out[2 * b + 1] = ((rp1[0] + rp1[1]) + (rp1[2] + rp1[3])) + br[1];
        atomicAdd(&counts[0], (unsigned)(rc1[0] + rc1[1] + rc1[2] + rc1[3]));
        atomicAdd(&counts[1], (unsigned)(rc2[0] + rc2[1] + rc2[2] + rc2[3]));
    }
}

__global__ void snn_finalize(const unsigned int* __restrict__ counts,
                             float* __restrict__ out) {
    if (threadIdx.x < 2)
        out[512 + threadIdx.x] = (float)counts[threadIdx.x] / 65536000.0f; // T*B*256
}

extern "C" void kernel_launch(void* const* d_in, const int* in_sizes, int n_in,
                              void* d_out, int out_size, void* d_ws, size_t ws_size,
                              hipStream_t stream) {
    const float* spikes = (const float*)d_in[0];
    const float* W1     = (const float*)d_in[1];
    const float* b1     = (const float*)d_in[2];
    const float* W2     = (const float*)d_in[3];
    const float* b2     = (const float*)d_in[4];
    const float* Wr     = (const float*)d_in[5];
    const float* br     = (const float*)d_in[6];
    float* out = (float*)d_out;

    float* W2T = (float*)d_ws;                                   // 256 KB
    unsigned int* counts = (unsigned int*)((char*)d_ws + (size_t)NH * NH * sizeof(float));

    snn_prep<<<256, 256, 0, stream>>>(W2, W2T, counts);
    snn_main<<<256, 256, 0, stream>>>(spikes, W1, b1, W2T, b2, Wr, br, out, counts);
    snn_finalize<<<1, 64, 0, stream>>>(counts, out);
}

// Round 3
// 1126.528 us; speedup vs baseline: 1.9466x; 1.0065x over previous
//
#include <hip/hip_runtime.h>
#include <stdint.h>

#define TSTEPS 1000
#define NB 256
#define NF 64
#define NH 256   // H1 == H2 == 256
#define CHUNK 8
#define NCH 125  // 125 * 8 == 1000, no tail

// Prep: transpose W2 (H2,H1) -> W2T[h1][h2] in d_ws for coalesced gathers,
// and zero the two global spike counters.
__global__ void snn_prep(const float* __restrict__ W2, float* __restrict__ W2T,
                         unsigned int* __restrict__ counts) {
    int idx = blockIdx.x * 256 + threadIdx.x;     // idx = h1*256 + h2
    W2T[idx] = W2[(idx & 255) * 256 + (idx >> 8)];
    if (idx < 2) counts[idx] = 0u;
}

// Main: one workgroup per batch, thread h = hidden unit (h1 for layer1 state,
// h2 for layer2 state). Time is processed in chunks of 8 steps: layer-1 for
// the whole chunk (no cross-wave deps, spk1 published to LDS), one barrier,
// then layer-2 for the whole chunk with pipelined independent L2 gathers.
// W1 row lives in VGPRs — pinned with inline-asm anchors so the compiler
// cannot sink the loads back into the loop (round-1 lesson: VGPR_Count=68
// proved w1 was memory-backed; the re-fetches were the dominant stall).
__launch_bounds__(256, 1)
__global__ void snn_main(const float* __restrict__ spikes,
                         const float* __restrict__ W1,
                         const float* __restrict__ b1,
                         const float* __restrict__ W2T,
                         const float* __restrict__ b2,
                         const float* __restrict__ Wr,
                         const float* __restrict__ br,
                         float* __restrict__ out,
                         unsigned int* __restrict__ counts) {
    const int b = blockIdx.x;
    const int h = threadIdx.x;
    const int lane = h & 63;
    const int wv = h >> 6;

    __shared__ unsigned char slist[CHUNK][256]; // per-step per-wave compacted spk1 lists
    __shared__ unsigned char scnt8[CHUNK * 4];  // per-step per-wave counts (bytes)
    __shared__ float rp0[4], rp1[4];
    __shared__ int rc1[4], rc2[4];

    // W1 row h -> registers: w1[f] = W1[h*64+f]. One-time 64 KB/block read.
    float w1[64];
    {
        const float4* W1v = (const float4*)(W1 + h * NF);
        #pragma unroll
        for (int i = 0; i < 16; ++i) {
            float4 v = W1v[i];
            w1[4 * i + 0] = v.x; w1[4 * i + 1] = v.y;
            w1[4 * i + 2] = v.z; w1[4 * i + 3] = v.w;
        }
    }
    // Pin w1 into VGPRs: opaque defs cannot be rematerialized as loads, and
    // at __launch_bounds__(256,1) the 512-VGPR budget keeps them resident.
    #pragma unroll
    for (int i = 0; i < 16; ++i) {
        asm("" : "+v"(w1[4 * i + 0]), "+v"(w1[4 * i + 1]),
                 "+v"(w1[4 * i + 2]), "+v"(w1[4 * i + 3]));
    }

    const float b1h = b1[h];
    const float b2h = b2[h];
    float mem1 = 0.f, mem2 = 0.f, mem2s = 0.f;
    int cnt1 = 0, cnt2 = 0;

    // Per-thread input prefetch: thread (any wave) needs x[t][b][lane] only.
    // Each wave's 64 lanes read 256 contiguous bytes -> coalesced; 4x wave
    // redundancy is served by L1. Prefetched one chunk ahead into registers.
    const size_t xstride = (size_t)NB * NF;
    const float* xbase = spikes + (size_t)b * NF + lane;
    float xq[CHUNK];
    #pragma unroll
    for (int tt = 0; tt < CHUNK; ++tt) {
        xq[tt] = xbase[(size_t)tt * xstride];
    }

    for (int c = 0; c < NCH; ++c) {
        __syncthreads();   // prev chunk's layer-2 slist reads complete; safe to overwrite

        // ---- layer 1: CHUNK steps, purely wave-local ----
        #pragma unroll
        for (int tt = 0; tt < CHUNK; ++tt) {
            unsigned long long xm = __ballot(xq[tt] > 0.f);
            // dense masked accumulation, 4 chains of 16 (ascending f within
            // each quarter) — bit-exact same order as the sparse ctz gather,
            // since adding +0.0f for inactive features is an exact identity.
            float a0 = 0.f, a1 = 0.f, a2 = 0.f, a3 = 0.f;
            #pragma unroll
            for (int f = 0; f < 16; ++f) {
                a0 += ((xm >> f) & 1ull) ? w1[f] : 0.f;
                a1 += ((xm >> (f + 16)) & 1ull) ? w1[f + 16] : 0.f;
                a2 += ((xm >> (f + 32)) & 1ull) ? w1[f + 32] : 0.f;
                a3 += ((xm >> (f + 48)) & 1ull) ? w1[f + 48] : 0.f;
            }
            float cur1 = b1h + ((a0 + a1) + (a2 + a3));
            float reset1 = (mem1 > 1.f) ? 1.f : 0.f;
            mem1 = 0.8187307530779818f * mem1 + cur1 - reset1;   // beta1 = exp(-1/5)
            bool s1 = (mem1 - 1.f) > 0.f;
            cnt1 += (int)s1;
            unsigned long long sm = __ballot(s1);
            if (lane == 0) scnt8[tt * 4 + wv] = (unsigned char)__popcll(sm);
            if (s1) {
                int rank = __popcll(sm & ((1ull << lane) - 1ull));
                slist[tt][(wv << 6) + rank] = (unsigned char)h;
            }
        }
        __syncthreads();   // slist/scnt published to all waves

        // prefetch next chunk's inputs; they land during the layer-2 phase
        {
            int cn = (c + 1 < NCH) ? c + 1 : 0;   // clamped dummy load on last chunk
            const float* xb = xbase + (size_t)cn * CHUNK * xstride;
            #pragma unroll
            for (int tt = 0; tt < CHUNK; ++tt) {
                xq[tt] = xb[(size_t)tt * xstride];
            }
        }

        // ---- layer 2: CHUNK steps, pipelined L2 gathers ----
        // Hoist all list metadata + first-4 indices into registers so the
        // unconditional gather loads for all 8 steps can be in flight at once.
        unsigned int cw[CHUNK], l0[CHUNK], l1[CHUNK], l2[CHUNK], l3[CHUNK];
        #pragma unroll
        for (int tt = 0; tt < CHUNK; ++tt) {
            cw[tt] = *(const unsigned int*)&scnt8[tt * 4];
            l0[tt] = *(const unsigned int*)&slist[tt][0];
            l1[tt] = *(const unsigned int*)&slist[tt][64];
            l2[tt] = *(const unsigned int*)&slist[tt][128];
            l3[tt] = *(const unsigned int*)&slist[tt][192];
        }
        const float* W2Th = W2T + h;
        #pragma unroll
        for (int tt = 0; tt < CHUNK; ++tt) {
            int c0 = cw[tt] & 255, c1 = (cw[tt] >> 8) & 255;
            int c2 = (cw[tt] >> 16) & 255, c3 = (cw[tt] >> 24) & 255;
            float q0 = 0.f, q1 = 0.f, q2 = 0.f, q3 = 0.f;
            unsigned int u0 = l0[tt], u1 = l1[tt], u2 = l2[tt], u3 = l3[tt];
            // first <=4 entries per wave-list, branch-free: stale bytes index
            // valid rows (0..255), their values are masked to 0 before the add,
            // so the summation order matches the guarded loop exactly.
            #pragma unroll
            for (int i = 0; i < 4; ++i) {
                float v0 = W2Th[(int)((u0 >> (8 * i)) & 255u) << 8];
                float v1 = W2Th[(int)((u1 >> (8 * i)) & 255u) << 8];
                float v2 = W2Th[(int)((u2 >> (8 * i)) & 255u) << 8];
                float v3 = W2Th[(int)((u3 >> (8 * i)) & 255u) << 8];
                q0 += (i < c0) ? v0 : 0.f;
                q1 += (i < c1) ? v1 : 0.f;
                q2 += (i < c2) ? v2 : 0.f;
                q3 += (i < c3) ? v3 : 0.f;
            }
            int nmax = max(max(c0, c1), max(c2, c3));
            if (nmax > 4) {   // rare overflow path (per-wave spike count > 4)
                const unsigned char* sl = slist[tt];
                for (int i = 4; i < nmax; ++i) {
                    if (i < c0) q0 += W2Th[(int)sl[i] << 8];
                    if (i < c1) q1 += W2Th[(int)sl[64 + i] << 8];
                    if (i < c2) q2 += W2Th[(int)sl[128 + i] << 8];
                    if (i < c3) q3 += W2Th[(int)sl[192 + i] << 8];
                }
            }
            float cur2 = b2h + ((q0 + q1) + (q2 + q3));
            float reset2 = (mem2 > 1.f) ? 1.f : 0.f;
            mem2 = 0.9048374180359595f * mem2 + cur2 - reset2;   // beta2 = exp(-1/10)
            bool s2 = (mem2 - 1.f) > 0.f;
            cnt2 += (int)s2;
            mem2s += mem2;
        }
    }

    // readout: out[b,:] = (mem2_sum/T) @ Wr.T + br ; block-level reduction
    float v = mem2s / 1000.0f;
    float p0 = v * Wr[h];
    float p1 = v * Wr[NH + h];
    int rcs1 = cnt1, rcs2 = cnt2;
    for (int off = 32; off > 0; off >>= 1) {
        p0 += __shfl_down(p0, off);
        p1 += __shfl_down(p1, off);
        rcs1 += __shfl_down(rcs1, off);
        rcs2 += __shfl_down(rcs2, off);
    }
    if (lane == 0) { rp0[wv] = p0; rp1[wv] = p1; rc1[wv] = rcs1; rc2[wv] = rcs2; }
    __syncthreads();
    if (h == 0) {
        out[2 * b]     = ((rp0[0] + rp0[1]) + (rp0[2] + rp0[3])) + br[0];
        out[2 * b + 1] = ((rp1[0] + rp1[1]) + (rp1[2] + rp1[3])) + br[1];
        atomicAdd(&counts[0], (unsigned)(rc1[0] + rc1[1] + rc1[2] + rc1[3]));
        atomicAdd(&counts[1], (unsigned)(rc2[0] + rc2[1] + rc2[2] + rc2[3]));
    }
}

__global__ void snn_finalize(const unsigned int* __restrict__ counts,
                             float* __restrict__ out) {
    if (threadIdx.x < 2)
        out[512 + threadIdx.x] = (float)counts[threadIdx.x] / 65536000.0f; // T*B*256
}

extern "C" void kernel_launch(void* const* d_in, const int* in_sizes, int n_in,
                              void* d_out, int out_size, void* d_ws, size_t ws_size,
                              hipStream_t stream) {
    const float* spikes = (const float*)d_in[0];
    const float* W1     = (const float*)d_in[1];
    const float* b1     = (const float*)d_in[2];
    const float* W2     = (const float*)d_in[3];
    const float* b2     = (const float*)d_in[4];
    const float* Wr     = (const float*)d_in[5];
    const float* br     = (const float*)d_in[6];
    float* out = (float*)d_out;

    float* W2T = (float*)d_ws;                                   // 256 KB
    unsigned int* counts = (unsigned int*)((char*)d_ws + (size_t)NH * NH * sizeof(float));

    snn_prep<<<256, 256, 0, stream>>>(W2, W2T, counts);
    snn_main<<<256, 256, 0, stream>>>(spikes, W1, b1, W2T, b2, Wr, br, out, counts);
    snn_finalize<<<1, 64, 0, stream>>>(counts, out);
}

// Round 4
// 736.417 us; speedup vs baseline: 2.9778x; 1.5297x over previous
//
#include <hip/hip_runtime.h>
#include <stdint.h>

#define TSTEPS 1000
#define NB 256
#define NF 64
#define NH 256   // H1 == H2 == 256
#define CHUNK 8
#define NCH 125  // 125 * 8 == 1000, no tail

// Prep: transpose W2 (H2,H1) -> W2T[h1][h2] in d_ws for coalesced gathers,
// and zero the two global spike counters.
__global__ void snn_prep(const float* __restrict__ W2, float* __restrict__ W2T,
                         unsigned int* __restrict__ counts) {
    int idx = blockIdx.x * 256 + threadIdx.x;     // idx = h1*256 + h2
    W2T[idx] = W2[(idx & 255) * 256 + (idx >> 8)];
    if (idx < 2) counts[idx] = 0u;
}

// Main: one 512-thread workgroup per batch, wave-specialized pipeline.
//   waves 0-3 (producer): own mem1[h], run layer 1 for chunk c, publish
//                         spk1 lists to slist[c&1].
//   waves 4-7 (consumer): own mem2[h], run layer 2 for chunk c-1 from
//                         slist[(c-1)&1], accumulate mem2_sum.
// One barrier per chunk; the two phases overlap on different waves and each
// SIMD carries 2 waves, so memory latency in one role is filled by VALU work
// of the other (round-3 lesson: at 1 wave/SIMD, 72% of cycles were
// un-fillable stalls; VALUBusy 28%).
__launch_bounds__(512, 2)
__global__ void snn_main(const float* __restrict__ spikes,
                         const float* __restrict__ W1,
                         const float* __restrict__ b1,
                         const float* __restrict__ W2T,
                         const float* __restrict__ b2,
                         const float* __restrict__ Wr,
                         const float* __restrict__ br,
                         float* __restrict__ out,
                         unsigned int* __restrict__ counts) {
    const int b = blockIdx.x;
    const int tid = threadIdx.x;
    const int lane = tid & 63;
    const int wv = tid >> 6;          // 0..7
    const bool producer = (wv < 4);
    const int h = tid & 255;          // hidden index within the role group

    __shared__ unsigned char slist[2][CHUNK][256]; // per-chunk-buf spk1 lists
    __shared__ unsigned char scnt8[2][CHUNK * 4];  // per-step per-wave counts
    __shared__ float rp0[4], rp1[4];
    __shared__ int rc1[4], rc2[4];

    // ---- producer state ----
    float w1[64];
    float mem1 = 0.f;
    int cnt1 = 0;
    float b1h = 0.f;
    float xq[CHUNK];
    const size_t xstride = (size_t)NB * NF;
    const float* xbase = spikes + (size_t)b * NF + lane;

    // ---- consumer state ----
    float mem2 = 0.f, mem2s = 0.f;
    int cnt2 = 0;
    float b2h = 0.f;

    if (producer) {
        // W1 row h -> registers: w1[f] = W1[h*64+f].
        const float4* W1v = (const float4*)(W1 + h * NF);
        #pragma unroll
        for (int i = 0; i < 16; ++i) {
            float4 v = W1v[i];
            w1[4 * i + 0] = v.x; w1[4 * i + 1] = v.y;
            w1[4 * i + 2] = v.z; w1[4 * i + 3] = v.w;
        }
        b1h = b1[h];
        // first-chunk input preload: lane reads x[t][b][lane]; each wave's 64
        // lanes read 256 contiguous bytes -> coalesced, 4x redundancy in L1.
        #pragma unroll
        for (int tt = 0; tt < CHUNK; ++tt) {
            xq[tt] = xbase[(size_t)tt * xstride];
        }
    } else {
        b2h = b2[h];
    }

    // layer-2 chunk body (consumer waves), reading chunk buffer cb
    auto consume = [&](int cb) {
        // hoist all list metadata + first-4 indices into registers so the
        // gather loads for all 8 steps can be in flight at once.
        unsigned int cw[CHUNK], l0[CHUNK], l1[CHUNK], l2[CHUNK], l3[CHUNK];
        #pragma unroll
        for (int tt = 0; tt < CHUNK; ++tt) {
            cw[tt] = *(const unsigned int*)&scnt8[cb][tt * 4];
            l0[tt] = *(const unsigned int*)&slist[cb][tt][0];
            l1[tt] = *(const unsigned int*)&slist[cb][tt][64];
            l2[tt] = *(const unsigned int*)&slist[cb][tt][128];
            l3[tt] = *(const unsigned int*)&slist[cb][tt][192];
        }
        const float* W2Th = W2T + h;
        #pragma unroll
        for (int tt = 0; tt < CHUNK; ++tt) {
            int c0 = cw[tt] & 255, c1 = (cw[tt] >> 8) & 255;
            int c2 = (cw[tt] >> 16) & 255, c3 = (cw[tt] >> 24) & 255;
            float q0 = 0.f, q1 = 0.f, q2 = 0.f, q3 = 0.f;
            unsigned int u0 = l0[tt], u1 = l1[tt], u2 = l2[tt], u3 = l3[tt];
            // first <=4 entries per wave-list, branch-free: stale bytes index
            // valid rows (0..255), values masked to 0 before the add, so the
            // summation order matches the guarded loop exactly.
            #pragma unroll
            for (int i = 0; i < 4; ++i) {
                float v0 = W2Th[(int)((u0 >> (8 * i)) & 255u) << 8];
                float v1 = W2Th[(int)((u1 >> (8 * i)) & 255u) << 8];
                float v2 = W2Th[(int)((u2 >> (8 * i)) & 255u) << 8];
                float v3 = W2Th[(int)((u3 >> (8 * i)) & 255u) << 8];
                q0 += (i < c0) ? v0 : 0.f;
                q1 += (i < c1) ? v1 : 0.f;
                q2 += (i < c2) ? v2 : 0.f;
                q3 += (i < c3) ? v3 : 0.f;
            }
            int nmax = max(max(c0, c1), max(c2, c3));
            if (nmax > 4) {   // rare overflow path (per-wave spike count > 4)
                const unsigned char* sl = &slist[cb][tt][0];
                for (int i = 4; i < nmax; ++i) {
                    if (i < c0) q0 += W2Th[(int)sl[i] << 8];
                    if (i < c1) q1 += W2Th[(int)sl[64 + i] << 8];
                    if (i < c2) q2 += W2Th[(int)sl[128 + i] << 8];
                    if (i < c3) q3 += W2Th[(int)sl[192 + i] << 8];
                }
            }
            float cur2 = b2h + ((q0 + q1) + (q2 + q3));
            float reset2 = (mem2 > 1.f) ? 1.f : 0.f;
            mem2 = 0.9048374180359595f * mem2 + cur2 - reset2;   // beta2 = exp(-1/10)
            bool s2 = (mem2 - 1.f) > 0.f;
            cnt2 += (int)s2;
            mem2s += mem2;
        }
    };

    for (int c = 0; c < NCH; ++c) {
        if (producer) {
            const int pb = c & 1;
            // ---- layer 1: CHUNK steps, purely wave-local ----
            #pragma unroll
            for (int tt = 0; tt < CHUNK; ++tt) {
                unsigned long long xm = __ballot(xq[tt] > 0.f);
                // dense masked accumulation, 4 chains of 16 (ascending f in
                // each quarter) — bit-exact same order as a sparse gather,
                // since adding +0.0f for inactive features is exact.
                float a0 = 0.f, a1 = 0.f, a2 = 0.f, a3 = 0.f;
                #pragma unroll
                for (int f = 0; f < 16; ++f) {
                    a0 += ((xm >> f) & 1ull) ? w1[f] : 0.f;
                    a1 += ((xm >> (f + 16)) & 1ull) ? w1[f + 16] : 0.f;
                    a2 += ((xm >> (f + 32)) & 1ull) ? w1[f + 32] : 0.f;
                    a3 += ((xm >> (f + 48)) & 1ull) ? w1[f + 48] : 0.f;
                }
                float cur1 = b1h + ((a0 + a1) + (a2 + a3));
                float reset1 = (mem1 > 1.f) ? 1.f : 0.f;
                mem1 = 0.8187307530779818f * mem1 + cur1 - reset1; // beta1=exp(-1/5)
                bool s1 = (mem1 - 1.f) > 0.f;
                cnt1 += (int)s1;
                unsigned long long sm = __ballot(s1);
                if (lane == 0) scnt8[pb][tt * 4 + wv] = (unsigned char)__popcll(sm);
                if (s1) {
                    int rank = __popcll(sm & ((1ull << lane) - 1ull));
                    slist[pb][tt][(wv << 6) + rank] = (unsigned char)h;
                }
            }
            // prefetch next chunk's inputs (land during next chunk's compute)
            int cn = (c + 1 < NCH) ? c + 1 : 0;  // clamped dummy load on last
            const float* xb = xbase + (size_t)cn * CHUNK * xstride;
            #pragma unroll
            for (int tt = 0; tt < CHUNK; ++tt) {
                xq[tt] = xb[(size_t)tt * xstride];
            }
        } else if (c > 0) {
            consume((c - 1) & 1);
        }
        __syncthreads();   // chunk handoff: slist[pb] ready; buffers swap
    }
    // pipeline epilogue: last chunk's layer 2
    if (!producer) {
        consume((NCH - 1) & 1);
    }

    // readout: out[b,:] = (mem2_sum/T) @ Wr.T + br ; role-local reductions
    if (producer) {
        int rcs1 = cnt1;
        for (int off = 32; off > 0; off >>= 1) rcs1 += __shfl_down(rcs1, off);
        if (lane == 0) rc1[wv] = rcs1;
    } else {
        float v = mem2s / 1000.0f;
        float p0 = v * Wr[h];
        float p1 = v * Wr[NH + h];
        int rcs2 = cnt2;
        for (int off = 32; off > 0; off >>= 1) {
            p0 += __shfl_down(p0, off);
            p1 += __shfl_down(p1, off);
            rcs2 += __shfl_down(rcs2, off);
        }
        if (lane == 0) { rp0[wv - 4] = p0; rp1[wv - 4] = p1; rc2[wv - 4] = rcs2; }
    }
    __syncthreads();
    if (tid == 0) {
        out[2 * b]     = ((rp0[0] + rp0[1]) + (rp0[2] + rp0[3])) + br[0];
        out[2 * b + 1] = ((rp1[0] + rp1[1]) + (rp1[2] + rp1[3])) + br[1];
        atomicAdd(&counts[0], (unsigned)(rc1[0] + rc1[1] + rc1[2] + rc1[3]));
        atomicAdd(&counts[1], (unsigned)(rc2[0] + rc2[1] + rc2[2] + rc2[3]));
    }
}

__global__ void snn_finalize(const unsigned int* __restrict__ counts,
                             float* __restrict__ out) {
    if (threadIdx.x < 2)
        out[512 + threadIdx.x] = (float)counts[threadIdx.x] / 65536000.0f; // T*B*256
}

extern "C" void kernel_launch(void* const* d_in, const int* in_sizes, int n_in,
                              void* d_out, int out_size, void* d_ws, size_t ws_size,
                              hipStream_t stream) {
    const float* spikes = (const float*)d_in[0];
    const float* W1     = (const float*)d_in[1];
    const float* b1     = (const float*)d_in[2];
    const float* W2     = (const float*)d_in[3];
    const float* b2     = (const float*)d_in[4];
    const float* Wr     = (const float*)d_in[5];
    const float* br     = (const float*)d_in[6];
    float* out = (float*)d_out;

    float* W2T = (float*)d_ws;                                   // 256 KB
    unsigned int* counts = (unsigned int*)((char*)d_ws + (size_t)NH * NH * sizeof(float));

    snn_prep<<<256, 256, 0, stream>>>(W2, W2T, counts);
    snn_main<<<256, 512, 0, stream>>>(spikes, W1, b1, W2T, b2, Wr, br, out, counts);
    snn_finalize<<<1, 64, 0, stream>>>(counts, out);
}

// Round 5
// 599.678 us; speedup vs baseline: 3.6567x; 1.2280x over previous
//
#include <hip/hip_runtime.h>
#include <stdint.h>

#define TSTEPS 1000
#define NB 256
#define NF 64
#define NH 256   // H1 == H2 == 256
#define CHUNK 8
#define NCH 125  // 125 * 8 == 1000, no tail

// Prep: transpose W2 (H2,H1) -> W2T[h1][h2] in d_ws for coalesced gathers,
// and zero the two global spike counters.
__global__ void snn_prep(const float* __restrict__ W2, float* __restrict__ W2T,
                         unsigned int* __restrict__ counts) {
    int idx = blockIdx.x * 256 + threadIdx.x;     // idx = h1*256 + h2
    W2T[idx] = W2[(idx & 255) * 256 + (idx >> 8)];
    if (idx < 2) counts[idx] = 0u;
}

// Main: one 512-thread workgroup per batch, wave-specialized pipeline.
//   waves 0-3 (producer): own mem1[h], run layer 1 for chunk c, publish
//                         spk1 lists to slist[c&1].
//   waves 4-7 (consumer): own mem2[h], run layer 2 for chunk c-1.
// Layer 1 is a straight FMA against the spike VALUES (exactly 0.0/1.0):
// bit-exact vs the masked-select (fma(1,w,a)=round(a+w); fma(0,w,a)=a),
// 1 VALU/feature instead of ~5. amdgpu_waves_per_eu(2,2) clamps the
// allocator to a 256-VGPR budget so w1 stays register-resident instead of
// being rematerialized as strided per-lane gathers (rounds 1-4: VGPR=68/72
// proved the occupancy heuristic kept spilling it).
__attribute__((amdgpu_flat_work_group_size(512, 512), amdgpu_waves_per_eu(2, 2)))
__global__ void snn_main(const float* __restrict__ spikes,
                         const float* __restrict__ W1,
                         const float* __restrict__ b1,
                         const float* __restrict__ W2T,
                         const float* __restrict__ b2,
                         const float* __restrict__ Wr,
                         const float* __restrict__ br,
                         float* __restrict__ out,
                         unsigned int* __restrict__ counts) {
    const int b = blockIdx.x;
    const int tid = threadIdx.x;
    const int lane = tid & 63;
    const int wv = tid >> 6;          // 0..7
    const bool producer = (wv < 4);
    const int h = tid & 255;          // hidden index within the role group

    __shared__ unsigned char slist[2][CHUNK][256]; // per-chunk-buf spk1 lists
    __shared__ unsigned char scnt8[2][CHUNK * 4];  // per-step per-wave counts
    __shared__ float rp0[4], rp1[4];
    __shared__ int rc1[4], rc2[4];

    // ---- producer state ----
    float w1[64];
    float mem1 = 0.f;
    int cnt1 = 0;
    float b1h = 0.f;
    float xq[CHUNK];                  // per-lane warm loads (L1 prefetch only)
    const size_t xstride = (size_t)NB * NF;
    const float* xrow_base = spikes + (size_t)b * NF;   // uniform row base
    const float* xbase = xrow_base + lane;              // per-lane warm ptr

    // ---- consumer state ----
    float mem2 = 0.f, mem2s = 0.f;
    int cnt2 = 0;
    float b2h = 0.f;

    if (producer) {
        // W1 row h -> registers: w1[f] = W1[h*64+f].
        const float4* W1v = (const float4*)(W1 + h * NF);
        #pragma unroll
        for (int i = 0; i < 16; ++i) {
            float4 v = W1v[i];
            w1[4 * i + 0] = v.x; w1[4 * i + 1] = v.y;
            w1[4 * i + 2] = v.z; w1[4 * i + 3] = v.w;
        }
        #pragma unroll
        for (int i = 0; i < 16; ++i) {
            asm("" : "+v"(w1[4 * i + 0]), "+v"(w1[4 * i + 1]),
                     "+v"(w1[4 * i + 2]), "+v"(w1[4 * i + 3]));
        }
        b1h = b1[h];
        // warm chunk 0's rows into L1 (coalesced 256B per row per wave)
        #pragma unroll
        for (int tt = 0; tt < CHUNK; ++tt) {
            xq[tt] = xbase[(size_t)tt * xstride];
        }
    } else {
        b2h = b2[h];
    }

    // layer-2 chunk body (consumer waves), reading chunk buffer cb
    auto consume = [&](int cb) {
        // hoist all list metadata + first-4 indices into registers so the
        // gather loads for all 8 steps can be in flight at once.
        unsigned int cw[CHUNK], l0[CHUNK], l1[CHUNK], l2[CHUNK], l3[CHUNK];
        #pragma unroll
        for (int tt = 0; tt < CHUNK; ++tt) {
            cw[tt] = *(const unsigned int*)&scnt8[cb][tt * 4];
            l0[tt] = *(const unsigned int*)&slist[cb][tt][0];
            l1[tt] = *(const unsigned int*)&slist[cb][tt][64];
            l2[tt] = *(const unsigned int*)&slist[cb][tt][128];
            l3[tt] = *(const unsigned int*)&slist[cb][tt][192];
        }
        const float* W2Th = W2T + h;
        #pragma unroll
        for (int tt = 0; tt < CHUNK; ++tt) {
            int c0 = cw[tt] & 255, c1 = (cw[tt] >> 8) & 255;
            int c2 = (cw[tt] >> 16) & 255, c3 = (cw[tt] >> 24) & 255;
            float q0 = 0.f, q1 = 0.f, q2 = 0.f, q3 = 0.f;
            unsigned int u0 = l0[tt], u1 = l1[tt], u2 = l2[tt], u3 = l3[tt];
            // first <=4 entries per wave-list, branch-free: stale bytes index
            // valid rows (0..255), values masked to 0 before the add, so the
            // summation order matches the guarded loop exactly.
            #pragma unroll
            for (int i = 0; i < 4; ++i) {
                float v0 = W2Th[(int)((u0 >> (8 * i)) & 255u) << 8];
                float v1 = W2Th[(int)((u1 >> (8 * i)) & 255u) << 8];
                float v2 = W2Th[(int)((u2 >> (8 * i)) & 255u) << 8];
                float v3 = W2Th[(int)((u3 >> (8 * i)) & 255u) << 8];
                q0 += (i < c0) ? v0 : 0.f;
                q1 += (i < c1) ? v1 : 0.f;
                q2 += (i < c2) ? v2 : 0.f;
                q3 += (i < c3) ? v3 : 0.f;
            }
            int nmax = max(max(c0, c1), max(c2, c3));
            if (nmax > 4) {   // rare overflow path (per-wave spike count > 4)
                const unsigned char* sl = &slist[cb][tt][0];
                for (int i = 4; i < nmax; ++i) {
                    if (i < c0) q0 += W2Th[(int)sl[i] << 8];
                    if (i < c1) q1 += W2Th[(int)sl[64 + i] << 8];
                    if (i < c2) q2 += W2Th[(int)sl[128 + i] << 8];
                    if (i < c3) q3 += W2Th[(int)sl[192 + i] << 8];
                }
            }
            float cur2 = b2h + ((q0 + q1) + (q2 + q3));
            float reset2 = (mem2 > 1.f) ? 1.f : 0.f;
            mem2 = 0.9048374180359595f * mem2 + cur2 - reset2;   // beta2 = exp(-1/10)
            bool s2 = (mem2 - 1.f) > 0.f;
            cnt2 += (int)s2;
            mem2s += mem2;
        }
    };

    for (int c = 0; c < NCH; ++c) {
        if (producer) {
            const int pb = c & 1;
            const int tb = c * CHUNK;
            // consume the warm loads issued a full chunk ago (long landed);
            // this keeps them live without exposing their latency.
            #pragma unroll
            for (int tt = 0; tt < CHUNK; ++tt) {
                asm volatile("" :: "v"(xq[tt]));
            }
            // ---- layer 1: CHUNK steps, straight FMA vs spike values ----
            #pragma unroll
            for (int tt = 0; tt < CHUNK; ++tt) {
                // uniform row read: all lanes same address -> broadcast loads
                const float4* xr4 =
                    (const float4*)(xrow_base + (size_t)(tb + tt) * xstride);
                float4 xv[16];
                #pragma unroll
                for (int i = 0; i < 16; ++i) xv[i] = xr4[i];
                // 4 chains of 16 features, ascending f in each quarter —
                // bit-exact same order/rounding as the masked-select version.
                float a[4];
                #pragma unroll
                for (int g = 0; g < 4; ++g) {
                    float acc = 0.f;
                    #pragma unroll
                    for (int q = 0; q < 4; ++q) {
                        float4 v = xv[g * 4 + q];
                        const int fb = g * 16 + q * 4;
                        acc += v.x * w1[fb + 0];
                        acc += v.y * w1[fb + 1];
                        acc += v.z * w1[fb + 2];
                        acc += v.w * w1[fb + 3];
                    }
                    a[g] = acc;
                }
                float cur1 = b1h + ((a[0] + a[1]) + (a[2] + a[3]));
                float reset1 = (mem1 > 1.f) ? 1.f : 0.f;
                mem1 = 0.8187307530779818f * mem1 + cur1 - reset1; // beta1=exp(-1/5)
                bool s1 = (mem1 - 1.f) > 0.f;
                cnt1 += (int)s1;
                unsigned long long sm = __ballot(s1);
                if (lane == 0) scnt8[pb][tt * 4 + wv] = (unsigned char)__popcll(sm);
                if (s1) {
                    int rank = __popcll(sm & ((1ull << lane) - 1ull));
                    slist[pb][tt][(wv << 6) + rank] = (unsigned char)h;
                }
            }
            // warm next chunk's rows (land during next chunk's compute)
            int cn = (c + 1 < NCH) ? c + 1 : 0;  // clamped dummy on last
            const float* xb = xbase + (size_t)cn * CHUNK * xstride;
            #pragma unroll
            for (int tt = 0; tt < CHUNK; ++tt) {
                xq[tt] = xb[(size_t)tt * xstride];
            }
        } else if (c > 0) {
            consume((c - 1) & 1);
        }
        __syncthreads();   // chunk handoff: slist[pb] ready; buffers swap
    }
    // pipeline epilogue: last chunk's layer 2
    if (!producer) {
        consume((NCH - 1) & 1);
    }

    // readout: out[b,:] = (mem2_sum/T) @ Wr.T + br ; role-local reductions
    if (producer) {
        int rcs1 = cnt1;
        for (int off = 32; off > 0; off >>= 1) rcs1 += __shfl_down(rcs1, off);
        if (lane == 0) rc1[wv] = rcs1;
    } else {
        float v = mem2s / 1000.0f;
        float p0 = v * Wr[h];
        float p1 = v * Wr[NH + h];
        int rcs2 = cnt2;
        for (int off = 32; off > 0; off >>= 1) {
            p0 += __shfl_down(p0, off);
            p1 += __shfl_down(p1, off);
            rcs2 += __shfl_down(rcs2, off);
        }
        if (lane == 0) { rp0[wv - 4] = p0; rp1[wv - 4] = p1; rc2[wv - 4] = rcs2; }
    }
    __syncthreads();
    if (tid == 0) {
        out[2 * b]     = ((rp0[0] + rp0[1]) + (rp0[2] + rp0[3])) + br[0];
        out[2 * b + 1] = ((rp1[0] + rp1[1]) + (rp1[2] + rp1[3])) + br[1];
        atomicAdd(&counts[0], (unsigned)(rc1[0] + rc1[1] + rc1[2] + rc1[3]));
        atomicAdd(&counts[1], (unsigned)(rc2[0] + rc2[1] + rc2[2] + rc2[3]));
    }
}

__global__ void snn_finalize(const unsigned int* __restrict__ counts,
                             float* __restrict__ out) {
    if (threadIdx.x < 2)
        out[512 + threadIdx.x] = (float)counts[threadIdx.x] / 65536000.0f; // T*B*256
}

extern "C" void kernel_launch(void* const* d_in, const int* in_sizes, int n_in,
                              void* d_out, int out_size, void* d_ws, size_t ws_size,
                              hipStream_t stream) {
    const float* spikes = (const float*)d_in[0];
    const float* W1     = (const float*)d_in[1];
    const float* b1     = (const float*)d_in[2];
    const float* W2     = (const float*)d_in[3];
    const float* b2     = (const float*)d_in[4];
    const float* Wr     = (const float*)d_in[5];
    const float* br     = (const float*)d_in[6];
    float* out = (float*)d_out;

    float* W2T = (float*)d_ws;                                   // 256 KB
    unsigned int* counts = (unsigned int*)((char*)d_ws + (size_t)NH * NH * sizeof(float));

    snn_prep<<<256, 256, 0, stream>>>(W2, W2T, counts);
    snn_main<<<256, 512, 0, stream>>>(spikes, W1, b1, W2T, b2, Wr, br, out, counts);
    snn_finalize<<<1, 64, 0, stream>>>(counts, out);
}